// Round 11
// baseline (426.001 us; speedup 1.0000x reference)
//
#include <hip/hip_runtime.h>

// ---------------------------------------------------------------------------
// TraceLevelEncoder: 3x GCNConv -> segment-softmax attention pool -> GRU(2,seq=1,h0=0) -> proj
// Round 23: non-temporal hints in the gather (single-variable change vs R22).
//   Theory: gather's agg write stream (25.6MB l3) + col reads (3.2MB) evict
//   xs from the 4MB/XCD L2 while xs has 16x reuse -> inflates the 184MB miss
//   volume served at the ~3.6TB/s L3 fabric plateau. agg has no intra-kernel
//   reuse (consumer GEMM reads mostly cross-XCD -> L3 anyway); col is
//   read-once-per-wave. Fix: __builtin_nontemporal_store(agg) +
//   __builtin_nontemporal_load(col) in k_gather_bf16 ONLY. GEMM C stores
//   keep caching (A-read reuse measured). Everything else identical to R22
//   (quartile fill, 64^2 C-staged GEMMs, x4-unrolled softmax).
// ---------------------------------------------------------------------------

#define N_GRAPHS 256
#define GRU_H 256
#define SCAN_CHUNK 2048   // 256 threads x 8 elements

typedef __attribute__((ext_vector_type(8))) short short8;   // 8 bf16 (4 VGPRs)
typedef __attribute__((ext_vector_type(4))) float floatx4;  // 4 fp32 acc
typedef __attribute__((ext_vector_type(4))) unsigned int uint4v;  // 16B nt vec

typedef unsigned short ushort_t;
typedef unsigned int uint_t;

__device__ __forceinline__ float bflo(uint_t u) { return __uint_as_float(u << 16); }
__device__ __forceinline__ float bfhi(uint_t u) { return __uint_as_float(u & 0xffff0000u); }
__device__ __forceinline__ uint_t f2bf(float f) {           // RNE
    uint_t u = __float_as_uint(f);
    return (u + 0x7fffu + ((u >> 16) & 1u)) >> 16;
}
__device__ __forceinline__ uint_t pack2(float a, float b) {
    return f2bf(a) | (f2bf(b) << 16);
}

// ---- CSR build ------------------------------------------------------------
// counts: 4 planes of N ints, counts[q*N+d] = #edges to d with src in quartile q

__global__ void k_hist(const int* __restrict__ src, const int* __restrict__ dst,
                       int* __restrict__ counts, int E, int N,
                       int T1, int T2, int T3) {
    int ebase = (blockIdx.x * blockDim.x + threadIdx.x) * 4;
    if (ebase + 4 <= E) {
        int4 s4 = *(const int4*)(src + ebase);
        int4 d4 = *(const int4*)(dst + ebase);
        int ss[4] = {s4.x, s4.y, s4.z, s4.w};
        int dd[4] = {d4.x, d4.y, d4.z, d4.w};
#pragma unroll
        for (int j = 0; j < 4; ++j) {
            int q = (ss[j] >= T1) + (ss[j] >= T2) + (ss[j] >= T3);
            atomicAdd(&counts[q * N + dd[j]], 1);
        }
    } else {
        for (int j = 0; j < 4; ++j) {
            int e = ebase + j;
            if (e < E) {
                int s = src[e];
                int q = (s >= T1) + (s >= T2) + (s >= T3);
                atomicAdd(&counts[q * N + dst[e]], 1);
            }
        }
    }
}

__global__ __launch_bounds__(256) void k_scan1(const int* __restrict__ counts,
                                               int* __restrict__ rowptr,
                                               int* __restrict__ bsums,
                                               float* __restrict__ dinv, int n) {
    int b = blockIdx.x, t = threadIdx.x;
    int base = b * SCAN_CHUNK + t * 8;
    int v[8];
    int s = 0;
#pragma unroll
    for (int j = 0; j < 8; ++j) {
        int i = base + j;
        int c = 0;
        if (i < n) {
            c = counts[i] + counts[n + i] + counts[2 * n + i] + counts[3 * n + i];
            dinv[i] = rsqrtf((float)(c + 1));  // +1 self loop
        }
        v[j] = s;            // exclusive within thread
        s += c;
    }
    __shared__ int sd[256];
    sd[t] = s;
    __syncthreads();
    for (int off = 1; off < 256; off <<= 1) {
        int tmp = (t >= off) ? sd[t - off] : 0;
        __syncthreads();
        sd[t] += tmp;
        __syncthreads();
    }
    int texcl = sd[t] - s;
    if (t == 255) bsums[b] = sd[255];
#pragma unroll
    for (int j = 0; j < 8; ++j) {
        int i = base + j;
        if (i < n) rowptr[i] = texcl + v[j];
    }
}

// scan3: finalize rowptr, derive per-quartile cursors
__global__ __launch_bounds__(256) void k_scan3(int* __restrict__ rowptr,
                                               const int* __restrict__ counts,
                                               int* __restrict__ qcur,
                                               const int* __restrict__ bsums,
                                               int n, int nb) {
    int b = blockIdx.x, t = threadIdx.x;
    __shared__ int s_off;
    if (t == 0) {
        int off = 0, tot = 0;
        for (int i = 0; i < nb; ++i) {
            int v = bsums[i];
            if (i < b) off += v;
            tot += v;
        }
        s_off = off;
        if (b == 0) rowptr[n] = tot;
    }
    __syncthreads();
    int off = s_off;
    int base = b * SCAN_CHUNK + t * 8;
#pragma unroll
    for (int j = 0; j < 8; ++j) {
        int i = base + j;
        if (i < n) {
            int r = rowptr[i] + off;
            rowptr[i] = r;
            int c0 = counts[i], c1 = counts[n + i], c2 = counts[2 * n + i];
            qcur[i]         = r;
            qcur[n + i]     = r + c0;
            qcur[2 * n + i] = r + c0 + c1;
            qcur[3 * n + i] = r + c0 + c1 + c2;
        }
    }
}

// ---- packed independent kernels: fill | prescale | wt_all | split_all -----
// fill: 8 edges/thread, ONE atomic per edge to quartile cursor qcur[q][d].

__global__ __launch_bounds__(256) void k_pack(
    const int* __restrict__ src, const int* __restrict__ dst,
    int* __restrict__ qcur, int T1, int T2, int T3,
    int* __restrict__ col, int E,
    const float4* __restrict__ x, const float* __restrict__ dinv,
    uint4* __restrict__ xs, int N,
    const float* __restrict__ w0, const float* __restrict__ w1,
    const float* __restrict__ w2, ushort_t* __restrict__ wt0,
    ushort_t* __restrict__ wt1, ushort_t* __restrict__ wt2,
    const float* __restrict__ wih0, const float* __restrict__ wih1,
    const float* __restrict__ pw,
    ushort_t* __restrict__ sh0, ushort_t* __restrict__ sl0,
    ushort_t* __restrict__ sh1, ushort_t* __restrict__ sl1,
    ushort_t* __restrict__ sh2, ushort_t* __restrict__ sl2,
    int nf, int np, int nw) {
    int b = blockIdx.x, t = threadIdx.x;
    if (b < nf) {
        int ebase = b * 2048 + t * 8;
        if (ebase + 8 <= E) {
            int4 s0 = *(const int4*)(src + ebase);
            int4 s1 = *(const int4*)(src + ebase + 4);
            int4 d0 = *(const int4*)(dst + ebase);
            int4 d1 = *(const int4*)(dst + ebase + 4);
            int ss[8] = {s0.x, s0.y, s0.z, s0.w, s1.x, s1.y, s1.z, s1.w};
            int dd[8] = {d0.x, d0.y, d0.z, d0.w, d1.x, d1.y, d1.z, d1.w};
            int pos[8];
#pragma unroll
            for (int j = 0; j < 8; ++j) {
                int q = (ss[j] >= T1) + (ss[j] >= T2) + (ss[j] >= T3);
                pos[j] = atomicAdd(&qcur[q * N + dd[j]], 1);
            }
#pragma unroll
            for (int j = 0; j < 8; ++j) col[pos[j]] = ss[j];
        } else {
#pragma unroll
            for (int j = 0; j < 8; ++j) {
                int e = ebase + j;
                if (e < E) {
                    int s = src[e];
                    int q = (s >= T1) + (s >= T2) + (s >= T3);
                    int pos = atomicAdd(&qcur[q * N + dst[e]], 1);
                    col[pos] = s;
                }
            }
        }
    } else if (b < nf + np) {
        int idx = (b - nf) * 256 + t;   // chunk of 8 over N*64
        int n = idx >> 3;
        if (n < N) {
            float dn = dinv[n];
            float4 v0 = x[idx * 2], v1 = x[idx * 2 + 1];
            uint4 o;
            o.x = pack2(v0.x * dn, v0.y * dn);
            o.y = pack2(v0.z * dn, v0.w * dn);
            o.z = pack2(v1.x * dn, v1.y * dn);
            o.w = pack2(v1.z * dn, v1.w * dn);
            xs[idx] = o;
        }
    } else if (b < nf + np + nw) {
        int idx = (b - nf - np) * 256 + t;
        if (idx < 8192) {
            int k = idx >> 7, n = idx & 127;
            wt0[(size_t)n * 64 + k] = (ushort_t)f2bf(w0[idx]);
        } else if (idx < 40960) {
            int i = idx - 8192;
            int k = i >> 8, n = i & 255;
            wt1[(size_t)n * 128 + k] = (ushort_t)f2bf(w1[i]);
        } else if (idx < 172032) {
            int i = idx - 40960;
            int k = i >> 9, n = i & 511;
            wt2[(size_t)n * 256 + k] = (ushort_t)f2bf(w2[i]);
        }
    } else {
        int idx = (b - nf - np - nw) * 256 + t;
        const float* s; ushort_t* H; ushort_t* L; int i;
        if (idx < 393216)      { s = wih0; H = sh0; L = sl0; i = idx; }
        else if (idx < 589824) { s = wih1; H = sh1; L = sl1; i = idx - 393216; }
        else if (idx < 720896) { s = pw;   H = sh2; L = sl2; i = idx - 589824; }
        else return;
        float v = s[i];
        uint_t h = f2bf(v);
        H[i] = (ushort_t)h;
        L[i] = (ushort_t)f2bf(v - __uint_as_float(h << 16));
    }
}

// ---- Edge aggregation (gather over CSR), bf16, fp32 accum, 8x unrolled ----

__device__ __forceinline__ void acc8(float& a0, float& a1, float& a2, float& a3,
                                     float& a4, float& a5, float& a6, float& a7,
                                     const uint4& v) {
    a0 += bflo(v.x); a1 += bfhi(v.x); a2 += bflo(v.y); a3 += bfhi(v.y);
    a4 += bflo(v.z); a5 += bfhi(v.z); a6 += bflo(v.w); a7 += bfhi(v.w);
}

// flat gather (all layers, row-major in/out). Non-temporal col loads + agg
// stores: neither has intra-kernel reuse; keeps xs (16x reuse) resident in L2.
__global__ void k_gather_bf16(const uint4* __restrict__ xs, const int* __restrict__ rp,
                              const int* __restrict__ col, const float* __restrict__ dinv,
                              uint4* __restrict__ agg, int N, int shift /*log2(D/8)*/) {
    int idx = blockIdx.x * blockDim.x + threadIdx.x;
    int n = idx >> shift;
    if (n >= N) return;
    int c = idx & ((1 << shift) - 1);
    int C8 = 1 << shift;
    int a = rp[n], b = rp[n + 1];
    uint4 u = xs[(size_t)n * C8 + c];   // self loop (pre-scaled by dinv[n])
    float a0 = bflo(u.x), a1 = bfhi(u.x), a2 = bflo(u.y), a3 = bfhi(u.y);
    float a4 = bflo(u.z), a5 = bfhi(u.z), a6 = bflo(u.w), a7 = bfhi(u.w);
    int k = a;
    for (; k + 8 <= b; k += 8) {
        int ci[8];
#pragma unroll
        for (int j = 0; j < 8; ++j) ci[j] = __builtin_nontemporal_load(col + k + j);
        uint4 v[8];
#pragma unroll
        for (int j = 0; j < 8; ++j) v[j] = xs[(size_t)ci[j] * C8 + c];
#pragma unroll
        for (int j = 0; j < 8; ++j)
            acc8(a0, a1, a2, a3, a4, a5, a6, a7, v[j]);
    }
    for (; k + 4 <= b; k += 4) {
        int ci[4];
#pragma unroll
        for (int j = 0; j < 4; ++j) ci[j] = __builtin_nontemporal_load(col + k + j);
        uint4 v[4];
#pragma unroll
        for (int j = 0; j < 4; ++j) v[j] = xs[(size_t)ci[j] * C8 + c];
#pragma unroll
        for (int j = 0; j < 4; ++j)
            acc8(a0, a1, a2, a3, a4, a5, a6, a7, v[j]);
    }
    for (; k < b; ++k) {
        uint4 v = xs[(size_t)__builtin_nontemporal_load(col + k) * C8 + c];
        acc8(a0, a1, a2, a3, a4, a5, a6, a7, v);
    }
    float dn = dinv[n];
    uint4v o;
    o.x = pack2(a0 * dn, a1 * dn);
    o.y = pack2(a2 * dn, a3 * dn);
    o.z = pack2(a4 * dn, a5 * dn);
    o.w = pack2(a6 * dn, a7 * dn);
    __builtin_nontemporal_store(o, (uint4v*)&agg[idx]);
}

// ---- MFMA bf16 GEMM (GCN layers): C = postproc(A @ Wt^T + bias) -----------
// 64x64 block tile, BK=64, 4 waves 2x2, each wave 32x32 via 2x2 MFMAs.
// 1D grid, XCD-aware decode. Epilogue stages the C tile in LDS (reuse As)
// then writes 512 coalesced uint4/block (R18-measured: l3 47us).

__global__ __launch_bounds__(256) void k_gemm_mfma(
    const ushort_t* __restrict__ A, const ushort_t* __restrict__ Wt,
    const float* __restrict__ bias, const float* __restrict__ dinv,
    ushort_t* __restrict__ C, int M, int K, int Nout, int scale_out,
    const float* __restrict__ gate_w, float* __restrict__ gateArr,
    int mB, int bnShift) {
    int id = blockIdx.x;
    int xcd = id & 7;
    int k2 = id >> 3;
    int bnI = k2 & ((1 << bnShift) - 1);
    int bmI = (k2 >> bnShift) * 8 + xcd;
    if (bmI >= mB) return;
    int bm = bmI * 64, bn = bnI * 64;

    __shared__ ushort_t As[64 * 72];   // stride 72 bf16 (144B rows, 16B-aligned)
    __shared__ ushort_t Bs[64 * 72];
    int tid = threadIdx.x;
    int wave = tid >> 6, lane = tid & 63;
    int quad = lane >> 4, lr = lane & 15;
    int wm = (wave & 1) * 32, wn = (wave >> 1) * 32;

    floatx4 zero = {0.f, 0.f, 0.f, 0.f};
    floatx4 acc00 = zero, acc01 = zero, acc10 = zero, acc11 = zero;

    int r0 = tid >> 3,         ko0 = (tid & 7) * 8;
    int r1 = (tid + 256) >> 3, ko1 = ((tid + 256) & 7) * 8;

    for (int k0 = 0; k0 < K; k0 += 64) {
        int ar0 = min(bm + r0, M - 1);
        int ar1 = min(bm + r1, M - 1);
        uint4 av0 = *(const uint4*)(A + (size_t)ar0 * K + k0 + ko0);
        uint4 av1 = *(const uint4*)(A + (size_t)ar1 * K + k0 + ko1);
        uint4 bv0 = *(const uint4*)(Wt + (size_t)(bn + r0) * K + k0 + ko0);
        uint4 bv1 = *(const uint4*)(Wt + (size_t)(bn + r1) * K + k0 + ko1);
        __syncthreads();   // prev iter LDS reads done
        *(uint4*)&As[r0 * 72 + ko0] = av0;
        *(uint4*)&As[r1 * 72 + ko1] = av1;
        *(uint4*)&Bs[r0 * 72 + ko0] = bv0;
        *(uint4*)&Bs[r1 * 72 + ko1] = bv1;
        __syncthreads();
#pragma unroll
        for (int ks = 0; ks < 2; ++ks) {
            short8 af0 = *(short8*)&As[(wm + lr) * 72 + ks * 32 + quad * 8];
            short8 af1 = *(short8*)&As[(wm + 16 + lr) * 72 + ks * 32 + quad * 8];
            short8 bf0 = *(short8*)&Bs[(wn + lr) * 72 + ks * 32 + quad * 8];
            short8 bf1 = *(short8*)&Bs[(wn + 16 + lr) * 72 + ks * 32 + quad * 8];
            acc00 = __builtin_amdgcn_mfma_f32_16x16x32_bf16(af0, bf0, acc00, 0, 0, 0);
            acc01 = __builtin_amdgcn_mfma_f32_16x16x32_bf16(af0, bf1, acc01, 0, 0, 0);
            acc10 = __builtin_amdgcn_mfma_f32_16x16x32_bf16(af1, bf0, acc10, 0, 0, 0);
            acc11 = __builtin_amdgcn_mfma_f32_16x16x32_bf16(af1, bf1, acc11, 0, 0, 0);
        }
    }

    // epilogue: C/D layout col=lane&15, row=quad*4+r (m89-verified).
    // Stage bf16 tile into LDS (reuse As), then coalesced uint4 write-out.
    __syncthreads();             // all waves done reading As/Bs
    ushort_t* Cs = As;           // 64 rows x stride 72
    float gwv[2] = {0.f, 0.f};
    if (gate_w) {
        gwv[0] = gate_w[bn + wn + lr];
        gwv[1] = gate_w[bn + wn + 16 + lr];
    }
    float pg[2][4] = {};
#pragma unroll
    for (int mi = 0; mi < 2; ++mi) {
#pragma unroll
        for (int ni = 0; ni < 2; ++ni) {
            floatx4 acc = (mi == 0) ? (ni == 0 ? acc00 : acc01)
                                    : (ni == 0 ? acc10 : acc11);
            int cc = wn + ni * 16 + lr;          // in-tile col
            float bcol = bias[bn + cc];
#pragma unroll
            for (int r = 0; r < 4; ++r) {
                int rr = wm + mi * 16 + quad * 4 + r;   // in-tile row
                int row = bm + rr;
                float v = 0.0f;
                if (row < M) {
                    v = acc[r] + bcol;
                    v = fmaxf(v, 0.0f);
                    if (gate_w) pg[mi][r] += v * gwv[ni];
                    if (scale_out) v *= dinv[row];
                }
                Cs[rr * 72 + cc] = (ushort_t)f2bf(v);
            }
        }
    }
    if (gate_w) {
#pragma unroll
        for (int mi = 0; mi < 2; ++mi) {
#pragma unroll
            for (int r = 0; r < 4; ++r) {
                float p = pg[mi][r];
                p += __shfl_down(p, 8, 16);
                p += __shfl_down(p, 4, 16);
                p += __shfl_down(p, 2, 16);
                p += __shfl_down(p, 1, 16);
                if (lr == 0) {
                    int row = bm + wm + mi * 16 + quad * 4 + r;
                    if (row < M) atomicAdd(&gateArr[row], p);
                }
            }
        }
    }
    __syncthreads();             // C tile staged
    {
        int rr = tid >> 2;
        int cbase = (tid & 3) * 2;
        int grow = bm + rr;
        if (grow < M) {
#pragma unroll
            for (int c2 = 0; c2 < 2; ++c2) {
                int chunk = cbase + c2;          // 8-ushort chunk within row
                uint4 v = *(const uint4*)&Cs[rr * 72 + chunk * 8];
                *(uint4*)&C[(size_t)grow * Nout + bn + chunk * 8] = v;
            }
        }
    }
}

// ---- split-precision MFMA GEMM (GRU/proj): C_f32 = A @ W^T (+bias) --------

__global__ __launch_bounds__(256) void k_gemm3(
    const ushort_t* __restrict__ Ahi, const ushort_t* __restrict__ Alo,
    const ushort_t* __restrict__ Whi, const ushort_t* __restrict__ Wlo,
    const float* __restrict__ bias, float* __restrict__ C,
    int M, int K, int Nout) {
    __shared__ ushort_t AsH[64 * 72];
    __shared__ ushort_t AsL[64 * 72];
    __shared__ ushort_t BsH[64 * 72];
    __shared__ ushort_t BsL[64 * 72];
    int tid = threadIdx.x;
    int wave = tid >> 6, lane = tid & 63;
    int quad = lane >> 4, lr = lane & 15;
    int wm = (wave & 1) * 32, wn = (wave >> 1) * 32;
    int bm = blockIdx.x * 64, bn = blockIdx.y * 64;

    floatx4 zero = {0.f, 0.f, 0.f, 0.f};
    floatx4 acc00 = zero, acc01 = zero, acc10 = zero, acc11 = zero;

    int r0 = tid >> 3,         ko0 = (tid & 7) * 8;
    int r1 = (tid + 256) >> 3, ko1 = ((tid + 256) & 7) * 8;

    for (int k0 = 0; k0 < K; k0 += 64) {
        int ar0 = min(bm + r0, M - 1);
        int ar1 = min(bm + r1, M - 1);
        size_t a0o = (size_t)ar0 * K + k0 + ko0, a1o = (size_t)ar1 * K + k0 + ko1;
        size_t b0o = (size_t)(bn + r0) * K + k0 + ko0, b1o = (size_t)(bn + r1) * K + k0 + ko1;
        uint4 ah0 = *(const uint4*)(Ahi + a0o), ah1 = *(const uint4*)(Ahi + a1o);
        uint4 al0 = *(const uint4*)(Alo + a0o), al1 = *(const uint4*)(Alo + a1o);
        uint4 bh0 = *(const uint4*)(Whi + b0o), bh1 = *(const uint4*)(Whi + b1o);
        uint4 bl0 = *(const uint4*)(Wlo + b0o), bl1 = *(const uint4*)(Wlo + b1o);
        __syncthreads();
        *(uint4*)&AsH[r0 * 72 + ko0] = ah0; *(uint4*)&AsH[r1 * 72 + ko1] = ah1;
        *(uint4*)&AsL[r0 * 72 + ko0] = al0; *(uint4*)&AsL[r1 * 72 + ko1] = al1;
        *(uint4*)&BsH[r0 * 72 + ko0] = bh0; *(uint4*)&BsH[r1 * 72 + ko1] = bh1;
        *(uint4*)&BsL[r0 * 72 + ko0] = bl0; *(uint4*)&BsL[r1 * 72 + ko1] = bl1;
        __syncthreads();
#pragma unroll
        for (int ks = 0; ks < 2; ++ks) {
            int a0i = (wm + lr) * 72 + ks * 32 + quad * 8;
            int a1i = (wm + 16 + lr) * 72 + ks * 32 + quad * 8;
            int b0i = (wn + lr) * 72 + ks * 32 + quad * 8;
            int b1i = (wn + 16 + lr) * 72 + ks * 32 + quad * 8;
            short8 afh0 = *(short8*)&AsH[a0i], afh1 = *(short8*)&AsH[a1i];
            short8 afl0 = *(short8*)&AsL[a0i], afl1 = *(short8*)&AsL[a1i];
            short8 bfh0 = *(short8*)&BsH[b0i], bfh1 = *(short8*)&BsH[b1i];
            short8 bfl0 = *(short8*)&BsL[b0i], bfl1 = *(short8*)&BsL[b1i];
            acc00 = __builtin_amdgcn_mfma_f32_16x16x32_bf16(afh0, bfh0, acc00, 0, 0, 0);
            acc00 = __builtin_amdgcn_mfma_f32_16x16x32_bf16(afh0, bfl0, acc00, 0, 0, 0);
            acc00 = __builtin_amdgcn_mfma_f32_16x16x32_bf16(afl0, bfh0, acc00, 0, 0, 0);
            acc01 = __builtin_amdgcn_mfma_f32_16x16x32_bf16(afh0, bfh1, acc01, 0, 0, 0);
            acc01 = __builtin_amdgcn_mfma_f32_16x16x32_bf16(afh0, bfl1, acc01, 0, 0, 0);
            acc01 = __builtin_amdgcn_mfma_f32_16x16x32_bf16(afl0, bfh1, acc01, 0, 0, 0);
            acc10 = __builtin_amdgcn_mfma_f32_16x16x32_bf16(afh1, bfh0, acc10, 0, 0, 0);
            acc10 = __builtin_amdgcn_mfma_f32_16x16x32_bf16(afh1, bfl0, acc10, 0, 0, 0);
            acc10 = __builtin_amdgcn_mfma_f32_16x16x32_bf16(afl1, bfh0, acc10, 0, 0, 0);
            acc11 = __builtin_amdgcn_mfma_f32_16x16x32_bf16(afh1, bfh1, acc11, 0, 0, 0);
            acc11 = __builtin_amdgcn_mfma_f32_16x16x32_bf16(afh1, bfl1, acc11, 0, 0, 0);
            acc11 = __builtin_amdgcn_mfma_f32_16x16x32_bf16(afl1, bfh1, acc11, 0, 0, 0);
        }
    }

#pragma unroll
    for (int mi = 0; mi < 2; ++mi) {
#pragma unroll
        for (int ni = 0; ni < 2; ++ni) {
            floatx4 acc = (mi == 0) ? (ni == 0 ? acc00 : acc01)
                                    : (ni == 0 ? acc10 : acc11);
            int col = bn + wn + ni * 16 + lr;
            float bcol = bias ? bias[col] : 0.0f;
#pragma unroll
            for (int r = 0; r < 4; ++r) {
                int row = bm + wm + mi * 16 + quad * 4 + r;
                if (row < M)
                    C[(size_t)row * Nout + col] = acc[r] + bcol;
            }
        }
    }
}

// ---- GRU gate epilogue (h=0: gh = bhh exactly, h' = (1-z)*n) --------------

__global__ void k_gru_ep(const float* __restrict__ gi, const float* __restrict__ bih,
                         const float* __restrict__ bhh,
                         ushort_t* __restrict__ hhi, ushort_t* __restrict__ hlo, int G) {
    int idx = blockIdx.x * blockDim.x + threadIdx.x;
    int g = idx >> 8, j = idx & 255;
    if (g >= G) return;
    const float* row = gi + (size_t)g * 768;
    float ir = row[j]       + bih[j]       + bhh[j];
    float iz = row[j + 256] + bih[j + 256] + bhh[j + 256];
    float in = row[j + 512] + bih[j + 512];
    float r = 1.0f / (1.0f + expf(-ir));
    float z = 1.0f / (1.0f + expf(-iz));
    float nn = tanhf(in + r * bhh[j + 512]);
    float h = (1.0f - z) * nn;
    uint_t hi = f2bf(h);
    hhi[idx] = (ushort_t)hi;
    hlo[idx] = (ushort_t)f2bf(h - __uint_as_float(hi << 16));
}

// ---- segment softmax + weighted sum -> graph emb (bf16 split pair) --------

__global__ __launch_bounds__(256) void k_softmax_emb(
    const uint_t* __restrict__ x /*bf16 pairs*/, const float* __restrict__ gate,
    const int* __restrict__ batch, int N,
    ushort_t* __restrict__ embH, ushort_t* __restrict__ embL) {
    int g = blockIdx.x;
    int s, e;
    {
        int lo = 0, hi = N;
        while (lo < hi) { int mid = (lo + hi) >> 1; if (batch[mid] < g) lo = mid + 1; else hi = mid; }
        s = lo;
        lo = s; hi = N;
        while (lo < hi) { int mid = (lo + hi) >> 1; if (batch[mid] < g + 1) lo = mid + 1; else hi = mid; }
        e = lo;
    }
    __shared__ float red[256];
    __shared__ float sal[256];
    int tid = threadIdx.x;
    float m = -INFINITY;
    for (int i = s + tid; i < e; i += 256) m = fmaxf(m, gate[i]);
    red[tid] = m; __syncthreads();
    for (int off = 128; off > 0; off >>= 1) {
        if (tid < off) red[tid] = fmaxf(red[tid], red[tid + off]);
        __syncthreads();
    }
    m = red[0]; __syncthreads();
    float ssum = 0.f;
    for (int i = s + tid; i < e; i += 256) ssum += expf(gate[i] - m);
    red[tid] = ssum; __syncthreads();
    for (int off = 128; off > 0; off >>= 1) {
        if (tid < off) red[tid] += red[tid + off];
        __syncthreads();
    }
    float denom = red[0];
    float inv = (denom > 0.f) ? 1.0f / denom : 0.0f;
    float acc0 = 0.f, acc1 = 0.f;
    for (int base = s; base < e; base += 256) {
        int i = base + tid;
        __syncthreads();
        sal[tid] = (i < e) ? expf(gate[i] - m) * inv : 0.0f;
        __syncthreads();
        int cnt = min(256, e - base);
        int k = 0;
        for (; k + 4 <= cnt; k += 4) {      // x4 unroll: 4 indep row loads
            uint_t u0 = x[(size_t)(base + k) * 256 + tid];
            uint_t u1 = x[(size_t)(base + k + 1) * 256 + tid];
            uint_t u2 = x[(size_t)(base + k + 2) * 256 + tid];
            uint_t u3 = x[(size_t)(base + k + 3) * 256 + tid];
            float s0 = sal[k], s1 = sal[k + 1], s2 = sal[k + 2], s3 = sal[k + 3];
            acc0 += s0 * bflo(u0); acc1 += s0 * bfhi(u0);
            acc0 += s1 * bflo(u1); acc1 += s1 * bfhi(u1);
            acc0 += s2 * bflo(u2); acc1 += s2 * bfhi(u2);
            acc0 += s3 * bflo(u3); acc1 += s3 * bfhi(u3);
        }
        for (; k < cnt; ++k) {
            float a = sal[k];
            uint_t u = x[(size_t)(base + k) * 256 + tid];
            acc0 += a * bflo(u);
            acc1 += a * bfhi(u);
        }
    }
    int i0 = g * 512 + tid * 2;
    uint_t h0 = f2bf(acc0);
    uint_t h1 = f2bf(acc1);
    embH[i0]     = (ushort_t)h0;
    embH[i0 + 1] = (ushort_t)h1;
    embL[i0]     = (ushort_t)f2bf(acc0 - __uint_as_float(h0 << 16));
    embL[i0 + 1] = (ushort_t)f2bf(acc1 - __uint_as_float(h1 << 16));
}

// ---------------------------------------------------------------------------

extern "C" void kernel_launch(void* const* d_in, const int* in_sizes, int n_in,
                              void* d_out, int out_size, void* d_ws, size_t ws_size,
                              hipStream_t stream) {
    const float* x       = (const float*)d_in[0];
    const int*   ei      = (const int*)d_in[1];
    const int*   batch   = (const int*)d_in[2];
    const float* w0      = (const float*)d_in[3];
    const float* b0      = (const float*)d_in[4];
    const float* w1      = (const float*)d_in[5];
    const float* b1      = (const float*)d_in[6];
    const float* w2      = (const float*)d_in[7];
    const float* b2      = (const float*)d_in[8];
    const float* gate_w  = (const float*)d_in[9];
    const float* wih0    = (const float*)d_in[11];
    const float* bih0    = (const float*)d_in[13];
    const float* bhh0    = (const float*)d_in[14];
    const float* wih1    = (const float*)d_in[15];
    const float* bih1    = (const float*)d_in[17];
    const float* bhh1    = (const float*)d_in[18];
    const float* pw      = (const float*)d_in[19];
    const float* pb      = (const float*)d_in[20];
    float* out = (float*)d_out;

    const int N = in_sizes[2];        // 50000 nodes
    const int E = in_sizes[1] / 2;    // 800000 edges
    const int G = N_GRAPHS;           // 256 graphs

    char* base = (char*)d_ws;
    size_t off = 0;
    auto alloc = [&](size_t bytes) -> char* {
        char* p = base + off;
        off = (off + bytes + 255) & ~(size_t)255;
        return p;
    };
    ushort_t* bufA  = (ushort_t*)alloc((size_t)N * 512 * 2);  // xs / final x (bf16)
    ushort_t* bufB  = (ushort_t*)alloc((size_t)N * 512 * 2);  // agg (bf16)
    float* dinv     = (float*)alloc((size_t)N * 4);
    // zeroed range: gateArr, counts (single memset; adjacent in carve-up)
    float* gateArr  = (float*)alloc((size_t)N * 4);
    int*   counts   = (int*)alloc((size_t)4 * N * 4);   // 4 quartile planes
    int*   qcur     = (int*)alloc((size_t)4 * N * 4);   // 4 quartile cursors
    int*   rowptr   = (int*)alloc((size_t)(N + 1) * 4);
    int*   bsums    = (int*)alloc((size_t)256 * 4);
    int*   col      = (int*)alloc((size_t)E * 4);
    ushort_t* wt0   = (ushort_t*)alloc((size_t)128 * 64 * 2);
    ushort_t* wt1   = (ushort_t*)alloc((size_t)256 * 128 * 2);
    ushort_t* wt2   = (ushort_t*)alloc((size_t)512 * 256 * 2);
    ushort_t* ih0H  = (ushort_t*)alloc((size_t)768 * 512 * 2);
    ushort_t* ih0L  = (ushort_t*)alloc((size_t)768 * 512 * 2);
    ushort_t* ih1H  = (ushort_t*)alloc((size_t)768 * 256 * 2);
    ushort_t* ih1L  = (ushort_t*)alloc((size_t)768 * 256 * 2);
    ushort_t* pwH   = (ushort_t*)alloc((size_t)512 * 256 * 2);
    ushort_t* pwL   = (ushort_t*)alloc((size_t)512 * 256 * 2);
    ushort_t* embH  = (ushort_t*)alloc((size_t)G * 512 * 2);
    ushort_t* embL  = (ushort_t*)alloc((size_t)G * 512 * 2);
    ushort_t* h1H   = (ushort_t*)alloc((size_t)G * 256 * 2);
    ushort_t* h1L   = (ushort_t*)alloc((size_t)G * 256 * 2);
    ushort_t* h2H   = (ushort_t*)alloc((size_t)G * 256 * 2);
    ushort_t* h2L   = (ushort_t*)alloc((size_t)G * 256 * 2);
    float* gi       = (float*)alloc((size_t)G * 768 * 4);
    (void)ws_size; (void)n_in; (void)out_size;

    const int* src = ei;
    const int* dst = ei + E;

    const int nb = (N + SCAN_CHUNK - 1) / SCAN_CHUNK;   // 25 for N=50000
    const int T1 = N >> 2, T2 = N >> 1, T3 = (N >> 1) + (N >> 2);

    // zero gateArr + counts in one shot (adjacent in carve-up)
    size_t zbytes = (size_t)((char*)qcur - (char*)gateArr);
    hipMemsetAsync(gateArr, 0, zbytes, stream);

    // CSR build + dinv (quartile histogram -> rowptr + quartile cursors)
    k_hist<<<(E + 1023) / 1024, 256, 0, stream>>>(src, dst, counts, E, N, T1, T2, T3);
    k_scan1<<<nb, 256, 0, stream>>>(counts, rowptr, bsums, dinv, N);
    k_scan3<<<nb, 256, 0, stream>>>(rowptr, counts, qcur, bsums, N, nb);

    // packed: fill (8 edges/thread, 1 atomic/edge to quartile cursor) +
    //         prescale + wt_all + split_all
    int nf = (E + 2047) / 2048;
    int np = (N * 8 + 255) / 256;
    int nw = (172032 + 255) / 256;
    int ns = (720896 + 255) / 256;
    k_pack<<<nf + np + nw + ns, 256, 0, stream>>>(
        src, dst, qcur, T1, T2, T3, col, E,
        (const float4*)x, dinv, (uint4*)bufA, N,
        w0, w1, w2, wt0, wt1, wt2,
        wih0, wih1, pw, ih0H, ih0L, ih1H, ih1L, pwH, pwL,
        nf, np, nw);

    int mB = (N + 63) / 64;                 // 782
    int mBpad = ((mB + 7) / 8) * 8;         // 784 (XCD-padded)

    // layer 1: flat gather D=64, GEMM 64->128 (relu * dinv), bnN=2 (shift 1)
    k_gather_bf16<<<(N * 8 + 255) / 256, 256, 0, stream>>>((const uint4*)bufA, rowptr, col, dinv, (uint4*)bufB, N, 3);
    k_gemm_mfma<<<mBpad * 2, 256, 0, stream>>>(bufB, wt0, b0, dinv, bufA, N, 64, 128, 1, nullptr, nullptr, mB, 1);

    // layer 2: flat gather D=128, GEMM 128->256 (relu * dinv), bnN=4 (shift 2)
    k_gather_bf16<<<(N * 16 + 255) / 256, 256, 0, stream>>>((const uint4*)bufA, rowptr, col, dinv, (uint4*)bufB, N, 4);
    k_gemm_mfma<<<mBpad * 4, 256, 0, stream>>>(bufB, wt1, b1, dinv, bufA, N, 128, 256, 1, nullptr, nullptr, mB, 2);

    // layer 3: flat gather D=256, GEMM 256->512 (relu; fused gate), bnN=8 (shift 3)
    k_gather_bf16<<<(N * 32 + 255) / 256, 256, 0, stream>>>((const uint4*)bufA, rowptr, col, dinv, (uint4*)bufB, N, 5);
    k_gemm_mfma<<<mBpad * 8, 256, 0, stream>>>(bufB, wt2, b2, dinv, bufA, N, 256, 512, 0, gate_w, gateArr, mB, 3);

    // attention pool (gstart + emb-split folded in; gate_b cancels in softmax)
    k_softmax_emb<<<G, 256, 0, stream>>>((const uint_t*)bufA, gateArr, batch, N, embH, embL);

    // GRU layer 0: gi = emb @ wih0^T  (M=256, K=512, N=768), then gate math
    k_gemm3<<<dim3(G / 64, 12), 256, 0, stream>>>(embH, embL, ih0H, ih0L, nullptr, gi, G, 512, 768);
    k_gru_ep<<<G, 256, 0, stream>>>(gi, bih0, bhh0, h1H, h1L, G);

    // GRU layer 1: gi = h1 @ wih1^T  (M=256, K=256, N=768)
    k_gemm3<<<dim3(G / 64, 12), 256, 0, stream>>>(h1H, h1L, ih1H, ih1L, nullptr, gi, G, 256, 768);
    k_gru_ep<<<G, 256, 0, stream>>>(gi, bih1, bhh1, h2H, h2L, G);

    // projection: out = h2 @ pw^T + pb  (M=256, K=256, N=512)
    k_gemm3<<<dim3(G / 64, 8), 256, 0, stream>>>(h2H, h2L, pwH, pwL, pb, out, G, 256, 512);
}

// Round 12
// 412.244 us; speedup vs baseline: 1.0334x; 1.0334x over previous
//
#include <hip/hip_runtime.h>

// ---------------------------------------------------------------------------
// TraceLevelEncoder: 3x GCNConv -> segment-softmax attention pool -> GRU(2,seq=1,h0=0) -> proj
// Round 24: exact revert to R20 (415.1us, best measured). R23's NT hints
//   REGRESSED (+8.5us): col has wave-broadcast + cross-wave L2 reuse that NT
//   loads destroyed (FETCH 184->187MB), and NT agg stores added write
//   overhead. R21's 16-plane counters regressed (+36us), R22's softmax
//   unroll was neutral. Every component here is at its measured optimum:
//   - flat gathers: L3-fabric floor ~3.6TB/s (beat col-chunk R13, plane-split
//     R14, NT R23)
//   - 64^2 C-staged GEMM (beat scalar-epilogue R16, 128^2 R19)
//   - quartile-cursor fill (beat 1-sided R12, 2-sided R14/15, ILP-only R16,
//     16-plane R21)
// ---------------------------------------------------------------------------

#define N_GRAPHS 256
#define GRU_H 256
#define SCAN_CHUNK 2048   // 256 threads x 8 elements

typedef __attribute__((ext_vector_type(8))) short short8;   // 8 bf16 (4 VGPRs)
typedef __attribute__((ext_vector_type(4))) float floatx4;  // 4 fp32 acc

typedef unsigned short ushort_t;
typedef unsigned int uint_t;

__device__ __forceinline__ float bflo(uint_t u) { return __uint_as_float(u << 16); }
__device__ __forceinline__ float bfhi(uint_t u) { return __uint_as_float(u & 0xffff0000u); }
__device__ __forceinline__ uint_t f2bf(float f) {           // RNE
    uint_t u = __float_as_uint(f);
    return (u + 0x7fffu + ((u >> 16) & 1u)) >> 16;
}
__device__ __forceinline__ uint_t pack2(float a, float b) {
    return f2bf(a) | (f2bf(b) << 16);
}

// ---- CSR build ------------------------------------------------------------
// counts: 4 planes of N ints, counts[q*N+d] = #edges to d with src in quartile q

__global__ void k_hist(const int* __restrict__ src, const int* __restrict__ dst,
                       int* __restrict__ counts, int E, int N,
                       int T1, int T2, int T3) {
    int ebase = (blockIdx.x * blockDim.x + threadIdx.x) * 4;
    if (ebase + 4 <= E) {
        int4 s4 = *(const int4*)(src + ebase);
        int4 d4 = *(const int4*)(dst + ebase);
        int ss[4] = {s4.x, s4.y, s4.z, s4.w};
        int dd[4] = {d4.x, d4.y, d4.z, d4.w};
#pragma unroll
        for (int j = 0; j < 4; ++j) {
            int q = (ss[j] >= T1) + (ss[j] >= T2) + (ss[j] >= T3);
            atomicAdd(&counts[q * N + dd[j]], 1);
        }
    } else {
        for (int j = 0; j < 4; ++j) {
            int e = ebase + j;
            if (e < E) {
                int s = src[e];
                int q = (s >= T1) + (s >= T2) + (s >= T3);
                atomicAdd(&counts[q * N + dst[e]], 1);
            }
        }
    }
}

__global__ __launch_bounds__(256) void k_scan1(const int* __restrict__ counts,
                                               int* __restrict__ rowptr,
                                               int* __restrict__ bsums,
                                               float* __restrict__ dinv, int n) {
    int b = blockIdx.x, t = threadIdx.x;
    int base = b * SCAN_CHUNK + t * 8;
    int v[8];
    int s = 0;
#pragma unroll
    for (int j = 0; j < 8; ++j) {
        int i = base + j;
        int c = 0;
        if (i < n) {
            c = counts[i] + counts[n + i] + counts[2 * n + i] + counts[3 * n + i];
            dinv[i] = rsqrtf((float)(c + 1));  // +1 self loop
        }
        v[j] = s;            // exclusive within thread
        s += c;
    }
    __shared__ int sd[256];
    sd[t] = s;
    __syncthreads();
    for (int off = 1; off < 256; off <<= 1) {
        int tmp = (t >= off) ? sd[t - off] : 0;
        __syncthreads();
        sd[t] += tmp;
        __syncthreads();
    }
    int texcl = sd[t] - s;
    if (t == 255) bsums[b] = sd[255];
#pragma unroll
    for (int j = 0; j < 8; ++j) {
        int i = base + j;
        if (i < n) rowptr[i] = texcl + v[j];
    }
}

// scan3: finalize rowptr, derive per-quartile cursors
__global__ __launch_bounds__(256) void k_scan3(int* __restrict__ rowptr,
                                               const int* __restrict__ counts,
                                               int* __restrict__ qcur,
                                               const int* __restrict__ bsums,
                                               int n, int nb) {
    int b = blockIdx.x, t = threadIdx.x;
    __shared__ int s_off;
    if (t == 0) {
        int off = 0, tot = 0;
        for (int i = 0; i < nb; ++i) {
            int v = bsums[i];
            if (i < b) off += v;
            tot += v;
        }
        s_off = off;
        if (b == 0) rowptr[n] = tot;
    }
    __syncthreads();
    int off = s_off;
    int base = b * SCAN_CHUNK + t * 8;
#pragma unroll
    for (int j = 0; j < 8; ++j) {
        int i = base + j;
        if (i < n) {
            int r = rowptr[i] + off;
            rowptr[i] = r;
            int c0 = counts[i], c1 = counts[n + i], c2 = counts[2 * n + i];
            qcur[i]         = r;
            qcur[n + i]     = r + c0;
            qcur[2 * n + i] = r + c0 + c1;
            qcur[3 * n + i] = r + c0 + c1 + c2;
        }
    }
}

// ---- packed independent kernels: fill | prescale | wt_all | split_all -----
// fill: 8 edges/thread, ONE atomic per edge to quartile cursor qcur[q][d].

__global__ __launch_bounds__(256) void k_pack(
    const int* __restrict__ src, const int* __restrict__ dst,
    int* __restrict__ qcur, int T1, int T2, int T3,
    int* __restrict__ col, int E,
    const float4* __restrict__ x, const float* __restrict__ dinv,
    uint4* __restrict__ xs, int N,
    const float* __restrict__ w0, const float* __restrict__ w1,
    const float* __restrict__ w2, ushort_t* __restrict__ wt0,
    ushort_t* __restrict__ wt1, ushort_t* __restrict__ wt2,
    const float* __restrict__ wih0, const float* __restrict__ wih1,
    const float* __restrict__ pw,
    ushort_t* __restrict__ sh0, ushort_t* __restrict__ sl0,
    ushort_t* __restrict__ sh1, ushort_t* __restrict__ sl1,
    ushort_t* __restrict__ sh2, ushort_t* __restrict__ sl2,
    int nf, int np, int nw) {
    int b = blockIdx.x, t = threadIdx.x;
    if (b < nf) {
        int ebase = b * 2048 + t * 8;
        if (ebase + 8 <= E) {
            int4 s0 = *(const int4*)(src + ebase);
            int4 s1 = *(const int4*)(src + ebase + 4);
            int4 d0 = *(const int4*)(dst + ebase);
            int4 d1 = *(const int4*)(dst + ebase + 4);
            int ss[8] = {s0.x, s0.y, s0.z, s0.w, s1.x, s1.y, s1.z, s1.w};
            int dd[8] = {d0.x, d0.y, d0.z, d0.w, d1.x, d1.y, d1.z, d1.w};
            int pos[8];
#pragma unroll
            for (int j = 0; j < 8; ++j) {
                int q = (ss[j] >= T1) + (ss[j] >= T2) + (ss[j] >= T3);
                pos[j] = atomicAdd(&qcur[q * N + dd[j]], 1);
            }
#pragma unroll
            for (int j = 0; j < 8; ++j) col[pos[j]] = ss[j];
        } else {
#pragma unroll
            for (int j = 0; j < 8; ++j) {
                int e = ebase + j;
                if (e < E) {
                    int s = src[e];
                    int q = (s >= T1) + (s >= T2) + (s >= T3);
                    int pos = atomicAdd(&qcur[q * N + dst[e]], 1);
                    col[pos] = s;
                }
            }
        }
    } else if (b < nf + np) {
        int idx = (b - nf) * 256 + t;   // chunk of 8 over N*64
        int n = idx >> 3;
        if (n < N) {
            float dn = dinv[n];
            float4 v0 = x[idx * 2], v1 = x[idx * 2 + 1];
            uint4 o;
            o.x = pack2(v0.x * dn, v0.y * dn);
            o.y = pack2(v0.z * dn, v0.w * dn);
            o.z = pack2(v1.x * dn, v1.y * dn);
            o.w = pack2(v1.z * dn, v1.w * dn);
            xs[idx] = o;
        }
    } else if (b < nf + np + nw) {
        int idx = (b - nf - np) * 256 + t;
        if (idx < 8192) {
            int k = idx >> 7, n = idx & 127;
            wt0[(size_t)n * 64 + k] = (ushort_t)f2bf(w0[idx]);
        } else if (idx < 40960) {
            int i = idx - 8192;
            int k = i >> 8, n = i & 255;
            wt1[(size_t)n * 128 + k] = (ushort_t)f2bf(w1[i]);
        } else if (idx < 172032) {
            int i = idx - 40960;
            int k = i >> 9, n = i & 511;
            wt2[(size_t)n * 256 + k] = (ushort_t)f2bf(w2[i]);
        }
    } else {
        int idx = (b - nf - np - nw) * 256 + t;
        const float* s; ushort_t* H; ushort_t* L; int i;
        if (idx < 393216)      { s = wih0; H = sh0; L = sl0; i = idx; }
        else if (idx < 589824) { s = wih1; H = sh1; L = sl1; i = idx - 393216; }
        else if (idx < 720896) { s = pw;   H = sh2; L = sl2; i = idx - 589824; }
        else return;
        float v = s[i];
        uint_t h = f2bf(v);
        H[i] = (ushort_t)h;
        L[i] = (ushort_t)f2bf(v - __uint_as_float(h << 16));
    }
}

// ---- Edge aggregation (gather over CSR), bf16, fp32 accum, 8x unrolled ----

__device__ __forceinline__ void acc8(float& a0, float& a1, float& a2, float& a3,
                                     float& a4, float& a5, float& a6, float& a7,
                                     const uint4& v) {
    a0 += bflo(v.x); a1 += bfhi(v.x); a2 += bflo(v.y); a3 += bfhi(v.y);
    a4 += bflo(v.z); a5 += bfhi(v.z); a6 += bflo(v.w); a7 += bfhi(v.w);
}

// flat gather (all layers, row-major in/out)
__global__ void k_gather_bf16(const uint4* __restrict__ xs, const int* __restrict__ rp,
                              const int* __restrict__ col, const float* __restrict__ dinv,
                              uint4* __restrict__ agg, int N, int shift /*log2(D/8)*/) {
    int idx = blockIdx.x * blockDim.x + threadIdx.x;
    int n = idx >> shift;
    if (n >= N) return;
    int c = idx & ((1 << shift) - 1);
    int C8 = 1 << shift;
    int a = rp[n], b = rp[n + 1];
    uint4 u = xs[(size_t)n * C8 + c];   // self loop (pre-scaled by dinv[n])
    float a0 = bflo(u.x), a1 = bfhi(u.x), a2 = bflo(u.y), a3 = bfhi(u.y);
    float a4 = bflo(u.z), a5 = bfhi(u.z), a6 = bflo(u.w), a7 = bfhi(u.w);
    int k = a;
    for (; k + 8 <= b; k += 8) {
        int ci[8];
#pragma unroll
        for (int j = 0; j < 8; ++j) ci[j] = col[k + j];
        uint4 v[8];
#pragma unroll
        for (int j = 0; j < 8; ++j) v[j] = xs[(size_t)ci[j] * C8 + c];
#pragma unroll
        for (int j = 0; j < 8; ++j)
            acc8(a0, a1, a2, a3, a4, a5, a6, a7, v[j]);
    }
    for (; k + 4 <= b; k += 4) {
        int ci[4];
#pragma unroll
        for (int j = 0; j < 4; ++j) ci[j] = col[k + j];
        uint4 v[4];
#pragma unroll
        for (int j = 0; j < 4; ++j) v[j] = xs[(size_t)ci[j] * C8 + c];
#pragma unroll
        for (int j = 0; j < 4; ++j)
            acc8(a0, a1, a2, a3, a4, a5, a6, a7, v[j]);
    }
    for (; k < b; ++k) {
        uint4 v = xs[(size_t)col[k] * C8 + c];
        acc8(a0, a1, a2, a3, a4, a5, a6, a7, v);
    }
    float dn = dinv[n];
    uint4 o;
    o.x = pack2(a0 * dn, a1 * dn);
    o.y = pack2(a2 * dn, a3 * dn);
    o.z = pack2(a4 * dn, a5 * dn);
    o.w = pack2(a6 * dn, a7 * dn);
    agg[idx] = o;
}

// ---- MFMA bf16 GEMM (GCN layers): C = postproc(A @ Wt^T + bias) -----------
// 64x64 block tile, BK=64, 4 waves 2x2, each wave 32x32 via 2x2 MFMAs.
// 1D grid, XCD-aware decode. Epilogue stages the C tile in LDS (reuse As)
// then writes 512 coalesced uint4/block (R18-measured: l3 47us).

__global__ __launch_bounds__(256) void k_gemm_mfma(
    const ushort_t* __restrict__ A, const ushort_t* __restrict__ Wt,
    const float* __restrict__ bias, const float* __restrict__ dinv,
    ushort_t* __restrict__ C, int M, int K, int Nout, int scale_out,
    const float* __restrict__ gate_w, float* __restrict__ gateArr,
    int mB, int bnShift) {
    int id = blockIdx.x;
    int xcd = id & 7;
    int k2 = id >> 3;
    int bnI = k2 & ((1 << bnShift) - 1);
    int bmI = (k2 >> bnShift) * 8 + xcd;
    if (bmI >= mB) return;
    int bm = bmI * 64, bn = bnI * 64;

    __shared__ ushort_t As[64 * 72];   // stride 72 bf16 (144B rows, 16B-aligned)
    __shared__ ushort_t Bs[64 * 72];
    int tid = threadIdx.x;
    int wave = tid >> 6, lane = tid & 63;
    int quad = lane >> 4, lr = lane & 15;
    int wm = (wave & 1) * 32, wn = (wave >> 1) * 32;

    floatx4 zero = {0.f, 0.f, 0.f, 0.f};
    floatx4 acc00 = zero, acc01 = zero, acc10 = zero, acc11 = zero;

    int r0 = tid >> 3,         ko0 = (tid & 7) * 8;
    int r1 = (tid + 256) >> 3, ko1 = ((tid + 256) & 7) * 8;

    for (int k0 = 0; k0 < K; k0 += 64) {
        int ar0 = min(bm + r0, M - 1);
        int ar1 = min(bm + r1, M - 1);
        uint4 av0 = *(const uint4*)(A + (size_t)ar0 * K + k0 + ko0);
        uint4 av1 = *(const uint4*)(A + (size_t)ar1 * K + k0 + ko1);
        uint4 bv0 = *(const uint4*)(Wt + (size_t)(bn + r0) * K + k0 + ko0);
        uint4 bv1 = *(const uint4*)(Wt + (size_t)(bn + r1) * K + k0 + ko1);
        __syncthreads();   // prev iter LDS reads done
        *(uint4*)&As[r0 * 72 + ko0] = av0;
        *(uint4*)&As[r1 * 72 + ko1] = av1;
        *(uint4*)&Bs[r0 * 72 + ko0] = bv0;
        *(uint4*)&Bs[r1 * 72 + ko1] = bv1;
        __syncthreads();
#pragma unroll
        for (int ks = 0; ks < 2; ++ks) {
            short8 af0 = *(short8*)&As[(wm + lr) * 72 + ks * 32 + quad * 8];
            short8 af1 = *(short8*)&As[(wm + 16 + lr) * 72 + ks * 32 + quad * 8];
            short8 bf0 = *(short8*)&Bs[(wn + lr) * 72 + ks * 32 + quad * 8];
            short8 bf1 = *(short8*)&Bs[(wn + 16 + lr) * 72 + ks * 32 + quad * 8];
            acc00 = __builtin_amdgcn_mfma_f32_16x16x32_bf16(af0, bf0, acc00, 0, 0, 0);
            acc01 = __builtin_amdgcn_mfma_f32_16x16x32_bf16(af0, bf1, acc01, 0, 0, 0);
            acc10 = __builtin_amdgcn_mfma_f32_16x16x32_bf16(af1, bf0, acc10, 0, 0, 0);
            acc11 = __builtin_amdgcn_mfma_f32_16x16x32_bf16(af1, bf1, acc11, 0, 0, 0);
        }
    }

    // epilogue: C/D layout col=lane&15, row=quad*4+r (m89-verified).
    // Stage bf16 tile into LDS (reuse As), then coalesced uint4 write-out.
    __syncthreads();             // all waves done reading As/Bs
    ushort_t* Cs = As;           // 64 rows x stride 72
    float gwv[2] = {0.f, 0.f};
    if (gate_w) {
        gwv[0] = gate_w[bn + wn + lr];
        gwv[1] = gate_w[bn + wn + 16 + lr];
    }
    float pg[2][4] = {};
#pragma unroll
    for (int mi = 0; mi < 2; ++mi) {
#pragma unroll
        for (int ni = 0; ni < 2; ++ni) {
            floatx4 acc = (mi == 0) ? (ni == 0 ? acc00 : acc01)
                                    : (ni == 0 ? acc10 : acc11);
            int cc = wn + ni * 16 + lr;          // in-tile col
            float bcol = bias[bn + cc];
#pragma unroll
            for (int r = 0; r < 4; ++r) {
                int rr = wm + mi * 16 + quad * 4 + r;   // in-tile row
                int row = bm + rr;
                float v = 0.0f;
                if (row < M) {
                    v = acc[r] + bcol;
                    v = fmaxf(v, 0.0f);
                    if (gate_w) pg[mi][r] += v * gwv[ni];
                    if (scale_out) v *= dinv[row];
                }
                Cs[rr * 72 + cc] = (ushort_t)f2bf(v);
            }
        }
    }
    if (gate_w) {
#pragma unroll
        for (int mi = 0; mi < 2; ++mi) {
#pragma unroll
            for (int r = 0; r < 4; ++r) {
                float p = pg[mi][r];
                p += __shfl_down(p, 8, 16);
                p += __shfl_down(p, 4, 16);
                p += __shfl_down(p, 2, 16);
                p += __shfl_down(p, 1, 16);
                if (lr == 0) {
                    int row = bm + wm + mi * 16 + quad * 4 + r;
                    if (row < M) atomicAdd(&gateArr[row], p);
                }
            }
        }
    }
    __syncthreads();             // C tile staged
    {
        int rr = tid >> 2;
        int cbase = (tid & 3) * 2;
        int grow = bm + rr;
        if (grow < M) {
#pragma unroll
            for (int c2 = 0; c2 < 2; ++c2) {
                int chunk = cbase + c2;          // 8-ushort chunk within row
                uint4 v = *(const uint4*)&Cs[rr * 72 + chunk * 8];
                *(uint4*)&C[(size_t)grow * Nout + bn + chunk * 8] = v;
            }
        }
    }
}

// ---- split-precision MFMA GEMM (GRU/proj): C_f32 = A @ W^T (+bias) --------

__global__ __launch_bounds__(256) void k_gemm3(
    const ushort_t* __restrict__ Ahi, const ushort_t* __restrict__ Alo,
    const ushort_t* __restrict__ Whi, const ushort_t* __restrict__ Wlo,
    const float* __restrict__ bias, float* __restrict__ C,
    int M, int K, int Nout) {
    __shared__ ushort_t AsH[64 * 72];
    __shared__ ushort_t AsL[64 * 72];
    __shared__ ushort_t BsH[64 * 72];
    __shared__ ushort_t BsL[64 * 72];
    int tid = threadIdx.x;
    int wave = tid >> 6, lane = tid & 63;
    int quad = lane >> 4, lr = lane & 15;
    int wm = (wave & 1) * 32, wn = (wave >> 1) * 32;
    int bm = blockIdx.x * 64, bn = blockIdx.y * 64;

    floatx4 zero = {0.f, 0.f, 0.f, 0.f};
    floatx4 acc00 = zero, acc01 = zero, acc10 = zero, acc11 = zero;

    int r0 = tid >> 3,         ko0 = (tid & 7) * 8;
    int r1 = (tid + 256) >> 3, ko1 = ((tid + 256) & 7) * 8;

    for (int k0 = 0; k0 < K; k0 += 64) {
        int ar0 = min(bm + r0, M - 1);
        int ar1 = min(bm + r1, M - 1);
        size_t a0o = (size_t)ar0 * K + k0 + ko0, a1o = (size_t)ar1 * K + k0 + ko1;
        size_t b0o = (size_t)(bn + r0) * K + k0 + ko0, b1o = (size_t)(bn + r1) * K + k0 + ko1;
        uint4 ah0 = *(const uint4*)(Ahi + a0o), ah1 = *(const uint4*)(Ahi + a1o);
        uint4 al0 = *(const uint4*)(Alo + a0o), al1 = *(const uint4*)(Alo + a1o);
        uint4 bh0 = *(const uint4*)(Whi + b0o), bh1 = *(const uint4*)(Whi + b1o);
        uint4 bl0 = *(const uint4*)(Wlo + b0o), bl1 = *(const uint4*)(Wlo + b1o);
        __syncthreads();
        *(uint4*)&AsH[r0 * 72 + ko0] = ah0; *(uint4*)&AsH[r1 * 72 + ko1] = ah1;
        *(uint4*)&AsL[r0 * 72 + ko0] = al0; *(uint4*)&AsL[r1 * 72 + ko1] = al1;
        *(uint4*)&BsH[r0 * 72 + ko0] = bh0; *(uint4*)&BsH[r1 * 72 + ko1] = bh1;
        *(uint4*)&BsL[r0 * 72 + ko0] = bl0; *(uint4*)&BsL[r1 * 72 + ko1] = bl1;
        __syncthreads();
#pragma unroll
        for (int ks = 0; ks < 2; ++ks) {
            int a0i = (wm + lr) * 72 + ks * 32 + quad * 8;
            int a1i = (wm + 16 + lr) * 72 + ks * 32 + quad * 8;
            int b0i = (wn + lr) * 72 + ks * 32 + quad * 8;
            int b1i = (wn + 16 + lr) * 72 + ks * 32 + quad * 8;
            short8 afh0 = *(short8*)&AsH[a0i], afh1 = *(short8*)&AsH[a1i];
            short8 afl0 = *(short8*)&AsL[a0i], afl1 = *(short8*)&AsL[a1i];
            short8 bfh0 = *(short8*)&BsH[b0i], bfh1 = *(short8*)&BsH[b1i];
            short8 bfl0 = *(short8*)&BsL[b0i], bfl1 = *(short8*)&BsL[b1i];
            acc00 = __builtin_amdgcn_mfma_f32_16x16x32_bf16(afh0, bfh0, acc00, 0, 0, 0);
            acc00 = __builtin_amdgcn_mfma_f32_16x16x32_bf16(afh0, bfl0, acc00, 0, 0, 0);
            acc00 = __builtin_amdgcn_mfma_f32_16x16x32_bf16(afl0, bfh0, acc00, 0, 0, 0);
            acc01 = __builtin_amdgcn_mfma_f32_16x16x32_bf16(afh0, bfh1, acc01, 0, 0, 0);
            acc01 = __builtin_amdgcn_mfma_f32_16x16x32_bf16(afh0, bfl1, acc01, 0, 0, 0);
            acc01 = __builtin_amdgcn_mfma_f32_16x16x32_bf16(afl0, bfh1, acc01, 0, 0, 0);
            acc10 = __builtin_amdgcn_mfma_f32_16x16x32_bf16(afh1, bfh0, acc10, 0, 0, 0);
            acc10 = __builtin_amdgcn_mfma_f32_16x16x32_bf16(afh1, bfl0, acc10, 0, 0, 0);
            acc10 = __builtin_amdgcn_mfma_f32_16x16x32_bf16(afl1, bfh0, acc10, 0, 0, 0);
            acc11 = __builtin_amdgcn_mfma_f32_16x16x32_bf16(afh1, bfh1, acc11, 0, 0, 0);
            acc11 = __builtin_amdgcn_mfma_f32_16x16x32_bf16(afh1, bfl1, acc11, 0, 0, 0);
            acc11 = __builtin_amdgcn_mfma_f32_16x16x32_bf16(afl1, bfh1, acc11, 0, 0, 0);
        }
    }

#pragma unroll
    for (int mi = 0; mi < 2; ++mi) {
#pragma unroll
        for (int ni = 0; ni < 2; ++ni) {
            floatx4 acc = (mi == 0) ? (ni == 0 ? acc00 : acc01)
                                    : (ni == 0 ? acc10 : acc11);
            int col = bn + wn + ni * 16 + lr;
            float bcol = bias ? bias[col] : 0.0f;
#pragma unroll
            for (int r = 0; r < 4; ++r) {
                int row = bm + wm + mi * 16 + quad * 4 + r;
                if (row < M)
                    C[(size_t)row * Nout + col] = acc[r] + bcol;
            }
        }
    }
}

// ---- GRU gate epilogue (h=0: gh = bhh exactly, h' = (1-z)*n) --------------

__global__ void k_gru_ep(const float* __restrict__ gi, const float* __restrict__ bih,
                         const float* __restrict__ bhh,
                         ushort_t* __restrict__ hhi, ushort_t* __restrict__ hlo, int G) {
    int idx = blockIdx.x * blockDim.x + threadIdx.x;
    int g = idx >> 8, j = idx & 255;
    if (g >= G) return;
    const float* row = gi + (size_t)g * 768;
    float ir = row[j]       + bih[j]       + bhh[j];
    float iz = row[j + 256] + bih[j + 256] + bhh[j + 256];
    float in = row[j + 512] + bih[j + 512];
    float r = 1.0f / (1.0f + expf(-ir));
    float z = 1.0f / (1.0f + expf(-iz));
    float nn = tanhf(in + r * bhh[j + 512]);
    float h = (1.0f - z) * nn;
    uint_t hi = f2bf(h);
    hhi[idx] = (ushort_t)hi;
    hlo[idx] = (ushort_t)f2bf(h - __uint_as_float(hi << 16));
}

// ---- segment softmax + weighted sum -> graph emb (bf16 split pair) --------

__global__ __launch_bounds__(256) void k_softmax_emb(
    const uint_t* __restrict__ x /*bf16 pairs*/, const float* __restrict__ gate,
    const int* __restrict__ batch, int N,
    ushort_t* __restrict__ embH, ushort_t* __restrict__ embL) {
    int g = blockIdx.x;
    int s, e;
    {
        int lo = 0, hi = N;
        while (lo < hi) { int mid = (lo + hi) >> 1; if (batch[mid] < g) lo = mid + 1; else hi = mid; }
        s = lo;
        lo = s; hi = N;
        while (lo < hi) { int mid = (lo + hi) >> 1; if (batch[mid] < g + 1) lo = mid + 1; else hi = mid; }
        e = lo;
    }
    __shared__ float red[256];
    __shared__ float sal[256];
    int tid = threadIdx.x;
    float m = -INFINITY;
    for (int i = s + tid; i < e; i += 256) m = fmaxf(m, gate[i]);
    red[tid] = m; __syncthreads();
    for (int off = 128; off > 0; off >>= 1) {
        if (tid < off) red[tid] = fmaxf(red[tid], red[tid + off]);
        __syncthreads();
    }
    m = red[0]; __syncthreads();
    float ssum = 0.f;
    for (int i = s + tid; i < e; i += 256) ssum += expf(gate[i] - m);
    red[tid] = ssum; __syncthreads();
    for (int off = 128; off > 0; off >>= 1) {
        if (tid < off) red[tid] += red[tid + off];
        __syncthreads();
    }
    float denom = red[0];
    float inv = (denom > 0.f) ? 1.0f / denom : 0.0f;
    float acc0 = 0.f, acc1 = 0.f;
    for (int base = s; base < e; base += 256) {
        int i = base + tid;
        __syncthreads();
        sal[tid] = (i < e) ? expf(gate[i] - m) * inv : 0.0f;
        __syncthreads();
        int cnt = min(256, e - base);
        for (int k = 0; k < cnt; ++k) {
            float a = sal[k];
            uint_t u = x[(size_t)(base + k) * 256 + tid];
            acc0 += a * bflo(u);
            acc1 += a * bfhi(u);
        }
    }
    int i0 = g * 512 + tid * 2;
    uint_t h0 = f2bf(acc0);
    uint_t h1 = f2bf(acc1);
    embH[i0]     = (ushort_t)h0;
    embH[i0 + 1] = (ushort_t)h1;
    embL[i0]     = (ushort_t)f2bf(acc0 - __uint_as_float(h0 << 16));
    embL[i0 + 1] = (ushort_t)f2bf(acc1 - __uint_as_float(h1 << 16));
}

// ---------------------------------------------------------------------------

extern "C" void kernel_launch(void* const* d_in, const int* in_sizes, int n_in,
                              void* d_out, int out_size, void* d_ws, size_t ws_size,
                              hipStream_t stream) {
    const float* x       = (const float*)d_in[0];
    const int*   ei      = (const int*)d_in[1];
    const int*   batch   = (const int*)d_in[2];
    const float* w0      = (const float*)d_in[3];
    const float* b0      = (const float*)d_in[4];
    const float* w1      = (const float*)d_in[5];
    const float* b1      = (const float*)d_in[6];
    const float* w2      = (const float*)d_in[7];
    const float* b2      = (const float*)d_in[8];
    const float* gate_w  = (const float*)d_in[9];
    const float* wih0    = (const float*)d_in[11];
    const float* bih0    = (const float*)d_in[13];
    const float* bhh0    = (const float*)d_in[14];
    const float* wih1    = (const float*)d_in[15];
    const float* bih1    = (const float*)d_in[17];
    const float* bhh1    = (const float*)d_in[18];
    const float* pw      = (const float*)d_in[19];
    const float* pb      = (const float*)d_in[20];
    float* out = (float*)d_out;

    const int N = in_sizes[2];        // 50000 nodes
    const int E = in_sizes[1] / 2;    // 800000 edges
    const int G = N_GRAPHS;           // 256 graphs

    char* base = (char*)d_ws;
    size_t off = 0;
    auto alloc = [&](size_t bytes) -> char* {
        char* p = base + off;
        off = (off + bytes + 255) & ~(size_t)255;
        return p;
    };
    ushort_t* bufA  = (ushort_t*)alloc((size_t)N * 512 * 2);  // xs / final x (bf16)
    ushort_t* bufB  = (ushort_t*)alloc((size_t)N * 512 * 2);  // agg (bf16)
    float* dinv     = (float*)alloc((size_t)N * 4);
    // zeroed range: gateArr, counts (single memset; adjacent in carve-up)
    float* gateArr  = (float*)alloc((size_t)N * 4);
    int*   counts   = (int*)alloc((size_t)4 * N * 4);   // 4 quartile planes
    int*   qcur     = (int*)alloc((size_t)4 * N * 4);   // 4 quartile cursors
    int*   rowptr   = (int*)alloc((size_t)(N + 1) * 4);
    int*   bsums    = (int*)alloc((size_t)256 * 4);
    int*   col      = (int*)alloc((size_t)E * 4);
    ushort_t* wt0   = (ushort_t*)alloc((size_t)128 * 64 * 2);
    ushort_t* wt1   = (ushort_t*)alloc((size_t)256 * 128 * 2);
    ushort_t* wt2   = (ushort_t*)alloc((size_t)512 * 256 * 2);
    ushort_t* ih0H  = (ushort_t*)alloc((size_t)768 * 512 * 2);
    ushort_t* ih0L  = (ushort_t*)alloc((size_t)768 * 512 * 2);
    ushort_t* ih1H  = (ushort_t*)alloc((size_t)768 * 256 * 2);
    ushort_t* ih1L  = (ushort_t*)alloc((size_t)768 * 256 * 2);
    ushort_t* pwH   = (ushort_t*)alloc((size_t)512 * 256 * 2);
    ushort_t* pwL   = (ushort_t*)alloc((size_t)512 * 256 * 2);
    ushort_t* embH  = (ushort_t*)alloc((size_t)G * 512 * 2);
    ushort_t* embL  = (ushort_t*)alloc((size_t)G * 512 * 2);
    ushort_t* h1H   = (ushort_t*)alloc((size_t)G * 256 * 2);
    ushort_t* h1L   = (ushort_t*)alloc((size_t)G * 256 * 2);
    ushort_t* h2H   = (ushort_t*)alloc((size_t)G * 256 * 2);
    ushort_t* h2L   = (ushort_t*)alloc((size_t)G * 256 * 2);
    float* gi       = (float*)alloc((size_t)G * 768 * 4);
    (void)ws_size; (void)n_in; (void)out_size;

    const int* src = ei;
    const int* dst = ei + E;

    const int nb = (N + SCAN_CHUNK - 1) / SCAN_CHUNK;   // 25 for N=50000
    const int T1 = N >> 2, T2 = N >> 1, T3 = (N >> 1) + (N >> 2);

    // zero gateArr + counts in one shot (adjacent in carve-up)
    size_t zbytes = (size_t)((char*)qcur - (char*)gateArr);
    hipMemsetAsync(gateArr, 0, zbytes, stream);

    // CSR build + dinv (quartile histogram -> rowptr + quartile cursors)
    k_hist<<<(E + 1023) / 1024, 256, 0, stream>>>(src, dst, counts, E, N, T1, T2, T3);
    k_scan1<<<nb, 256, 0, stream>>>(counts, rowptr, bsums, dinv, N);
    k_scan3<<<nb, 256, 0, stream>>>(rowptr, counts, qcur, bsums, N, nb);

    // packed: fill (8 edges/thread, 1 atomic/edge to quartile cursor) +
    //         prescale + wt_all + split_all
    int nf = (E + 2047) / 2048;
    int np = (N * 8 + 255) / 256;
    int nw = (172032 + 255) / 256;
    int ns = (720896 + 255) / 256;
    k_pack<<<nf + np + nw + ns, 256, 0, stream>>>(
        src, dst, qcur, T1, T2, T3, col, E,
        (const float4*)x, dinv, (uint4*)bufA, N,
        w0, w1, w2, wt0, wt1, wt2,
        wih0, wih1, pw, ih0H, ih0L, ih1H, ih1L, pwH, pwL,
        nf, np, nw);

    int mB = (N + 63) / 64;                 // 782
    int mBpad = ((mB + 7) / 8) * 8;         // 784 (XCD-padded)

    // layer 1: flat gather D=64, GEMM 64->128 (relu * dinv), bnN=2 (shift 1)
    k_gather_bf16<<<(N * 8 + 255) / 256, 256, 0, stream>>>((const uint4*)bufA, rowptr, col, dinv, (uint4*)bufB, N, 3);
    k_gemm_mfma<<<mBpad * 2, 256, 0, stream>>>(bufB, wt0, b0, dinv, bufA, N, 64, 128, 1, nullptr, nullptr, mB, 1);

    // layer 2: flat gather D=128, GEMM 128->256 (relu * dinv), bnN=4 (shift 2)
    k_gather_bf16<<<(N * 16 + 255) / 256, 256, 0, stream>>>((const uint4*)bufA, rowptr, col, dinv, (uint4*)bufB, N, 4);
    k_gemm_mfma<<<mBpad * 4, 256, 0, stream>>>(bufB, wt1, b1, dinv, bufA, N, 128, 256, 1, nullptr, nullptr, mB, 2);

    // layer 3: flat gather D=256, GEMM 256->512 (relu; fused gate), bnN=8 (shift 3)
    k_gather_bf16<<<(N * 32 + 255) / 256, 256, 0, stream>>>((const uint4*)bufA, rowptr, col, dinv, (uint4*)bufB, N, 5);
    k_gemm_mfma<<<mBpad * 8, 256, 0, stream>>>(bufB, wt2, b2, dinv, bufA, N, 256, 512, 0, gate_w, gateArr, mB, 3);

    // attention pool (gstart + emb-split folded in; gate_b cancels in softmax)
    k_softmax_emb<<<G, 256, 0, stream>>>((const uint_t*)bufA, gateArr, batch, N, embH, embL);

    // GRU layer 0: gi = emb @ wih0^T  (M=256, K=512, N=768), then gate math
    k_gemm3<<<dim3(G / 64, 12), 256, 0, stream>>>(embH, embL, ih0H, ih0L, nullptr, gi, G, 512, 768);
    k_gru_ep<<<G, 256, 0, stream>>>(gi, bih0, bhh0, h1H, h1L, G);

    // GRU layer 1: gi = h1 @ wih1^T  (M=256, K=256, N=768)
    k_gemm3<<<dim3(G / 64, 12), 256, 0, stream>>>(h1H, h1L, ih1H, ih1L, nullptr, gi, G, 256, 768);
    k_gru_ep<<<G, 256, 0, stream>>>(gi, bih1, bhh1, h2H, h2L, G);

    // projection: out = h2 @ pw^T + pb  (M=256, K=256, N=512)
    k_gemm3<<<dim3(G / 64, 8), 256, 0, stream>>>(h2H, h2L, pwH, pwL, pb, out, G, 256, 512);
}